// Round 1
// baseline (15998.625 us; speedup 1.0000x reference)
//
#include <hip/hip_runtime.h>
#include <math.h>

// ---------------------------------------------------------------------------
// PureTriXButterfly: fourier-encode -> proj+LN+GELU -> 3x { router top-4 of 16
// tiles, per-tile 2-layer FFN (gathered grouped GEMM), gated scatter-add,
// residual LN } -> two heads -> (B,11) logits.
// Round 1: all fp32 vector math (no MFMA) - correctness + baseline.
// Top-4 sparsity exploited: 4x fewer FLOPs than dense reference.
// ---------------------------------------------------------------------------

constexpr int D    = 1024;
constexpr int T    = 16;
constexpr int KSEL = 4;
constexpr int BM = 64, BN = 64, BK = 16;

__device__ __forceinline__ float gelu_f(float v) {
    return 0.5f * v * (1.0f + erff(v * 0.70710678118654752440f));
}

// ---------------- input encode: fourier -> @Win -> LN -> GELU --------------
__global__ __launch_bounds__(256) void encode_kernel(
    const int* __restrict__ A, const int* __restrict__ Bv,
    const float* __restrict__ Win, const float* __restrict__ bin_,
    const float* __restrict__ g_in, const float* __restrict__ b_ln,
    float* __restrict__ x)
{
    const int row = blockIdx.x, tid = threadIdx.x;
    const float c = (float)(6.283185307179586476925286766559 / 16.0);
    float feat[32];
    const float xa = (float)A[row] * c;
    const float xb = (float)Bv[row] * c;
#pragma unroll
    for (int k = 0; k < 8; ++k) {
        const float f = (float)(1 << k);
        float aa = xa * f, ab = xb * f;
        feat[k]      = sinf(aa);
        feat[8 + k]  = cosf(aa);
        feat[16 + k] = sinf(ab);
        feat[24 + k] = cosf(ab);
    }
    const int d = tid << 2;
    float4 acc = *(const float4*)(bin_ + d);
#pragma unroll
    for (int f = 0; f < 32; ++f) {
        const float4 w = *(const float4*)(Win + (size_t)f * D + d);
        const float ff = feat[f];
        acc.x += ff * w.x; acc.y += ff * w.y; acc.z += ff * w.z; acc.w += ff * w.w;
    }
    __shared__ float red[256];
    red[tid] = acc.x + acc.y + acc.z + acc.w;
    __syncthreads();
    for (int st = 128; st > 0; st >>= 1) { if (tid < st) red[tid] += red[tid + st]; __syncthreads(); }
    const float mean = red[0] * (1.0f / 1024.0f);
    __syncthreads();
    float dx0 = acc.x - mean, dx1 = acc.y - mean, dx2 = acc.z - mean, dx3 = acc.w - mean;
    red[tid] = dx0 * dx0 + dx1 * dx1 + dx2 * dx2 + dx3 * dx3;
    __syncthreads();
    for (int st = 128; st > 0; st >>= 1) { if (tid < st) red[tid] += red[tid + st]; __syncthreads(); }
    const float rstd = rsqrtf(red[0] * (1.0f / 1024.0f) + 1e-5f);
    const float4 g4 = *(const float4*)(g_in + d);
    const float4 b4 = *(const float4*)(b_ln + d);
    float4 o;
    o.x = gelu_f(dx0 * rstd * g4.x + b4.x);
    o.y = gelu_f(dx1 * rstd * g4.y + b4.y);
    o.z = gelu_f(dx2 * rstd * g4.z + b4.z);
    o.w = gelu_f(dx3 * rstd * g4.w + b4.w);
    *(float4*)(x + (size_t)row * D + d) = o;
}

// ---------------- per-layer init: zero out_acc, rowlist=-1, counts=0 -------
__global__ __launch_bounds__(256) void init_layer_kernel(
    float* __restrict__ outacc, int* __restrict__ rowlist, int* __restrict__ counts,
    long n, int maxslots)
{
    const long i = (long)blockIdx.x * blockDim.x + threadIdx.x;
    if (i < n) outacc[i] = 0.0f;
    if (i < maxslots) rowlist[i] = -1;
    if (i < T) counts[i] = 0;
}

// ---------------- router: logits, softmax, top-4 ---------------------------
__global__ __launch_bounds__(64) void router_kernel(
    const float* __restrict__ x, const float* __restrict__ Wr, int layer,
    float* __restrict__ gates, int* __restrict__ topi, int* __restrict__ counts)
{
    const int row = blockIdx.x, lane = threadIdx.x;
    __shared__ float xs[D];
    __shared__ float ls[T];
    for (int j = lane; j < D / 4; j += 64)
        *(float4*)&xs[j * 4] = *(const float4*)(x + (size_t)row * D + j * 4);
    __syncthreads();
    const int t = lane & 15, seg = lane >> 4;
    const float* wr = Wr + (size_t)layer * D * T;
    float acc = 0.0f;
    const int d0 = seg * 256;
    for (int j = 0; j < 256; ++j) {
        const int d = d0 + j;
        acc += xs[d] * wr[d * T + t];
    }
    acc += __shfl_down(acc, 32);
    acc += __shfl_down(acc, 16);
    if (lane < 16) ls[lane] = acc;
    __syncthreads();
    if (lane == 0) {
        float m = ls[0];
        for (int i = 1; i < 16; ++i) m = fmaxf(m, ls[i]);
        float p[16], ssum = 0.0f;
        for (int i = 0; i < 16; ++i) { p[i] = expf(ls[i] - m); ssum += p[i]; }
        const float inv = 1.0f / ssum;
        bool sel[16];
        for (int i = 0; i < 16; ++i) sel[i] = false;
        for (int j = 0; j < KSEL; ++j) {
            int best = 0; float bvv = -1e30f;
            for (int i = 0; i < 16; ++i)
                if (!sel[i] && ls[i] > bvv) { bvv = ls[i]; best = i; }
            sel[best] = true;
            topi[row * KSEL + j]  = best;
            gates[row * KSEL + j] = p[best] * inv;
            atomicAdd(&counts[best], 1);
        }
    }
}

// ---------------- scan: padded per-tile offsets ----------------------------
__global__ void scan_kernel(const int* __restrict__ counts, int* __restrict__ offp,
                            int* __restrict__ cur)
{
    if (threadIdx.x == 0) {
        int off = 0;
        for (int t = 0; t < T; ++t) {
            offp[t] = off;
            cur[t] = 0;
            off += ((counts[t] + BM - 1) / BM) * BM;
        }
        offp[T] = off;
    }
}

// ---------------- scatter rows into tile slot lists ------------------------
__global__ __launch_bounds__(256) void scatter_kernel(
    const int* __restrict__ topi, const float* __restrict__ gates,
    const int* __restrict__ offp, int* __restrict__ cur,
    int* __restrict__ rowlist, float* __restrict__ slotgate, int Bn)
{
    const int row = blockIdx.x * blockDim.x + threadIdx.x;
    if (row >= Bn) return;
    for (int j = 0; j < KSEL; ++j) {
        const int t = topi[row * KSEL + j];
        const int pos = atomicAdd(&cur[t], 1);
        const int s = offp[t] + pos;
        rowlist[s] = row;
        slotgate[s] = gates[row * KSEL + j];
    }
}

// ---------------- grouped gather-GEMM (+bias, opt. GELU) -------------------
// H[slot_local, n] = act( sum_k X[row(slot), k] * W_t[k*ldw + n] + bias_t[n] )
// offp != null: tile-grouped FFN mode (tile from padded offsets, gather rows).
// offp == null: plain mode (row = slot), used by head GEMMs.
__global__ __launch_bounds__(256) void gemm_gather_kernel(
    const float* __restrict__ Xsrc, const int* __restrict__ rowlist,
    const int* __restrict__ offp, const float* __restrict__ Wbase,
    const float* __restrict__ biasbase, float* __restrict__ Hout,
    int s0, int Kdim, int ldw, int plainM, int applyGelu)
{
    const int slot0 = s0 + blockIdx.x * BM;
    const float* W;
    const float* bias;
    if (offp) {
        if (slot0 >= offp[T]) return;
        int t = 0;
        while (offp[t + 1] <= slot0) ++t;
        W = Wbase + (size_t)t * Kdim * ldw;
        bias = biasbase + (size_t)t * ldw;
    } else {
        if (slot0 >= plainM) return;
        W = Wbase; bias = biasbase;
    }
    const int tid = threadIdx.x;
    __shared__ float As[BK][BM];
    __shared__ float Bs[BK][BN];
    const int ar = tid >> 2, ak = (tid & 3) << 2;
    const int bkr = tid >> 4, bnc = (tid & 15) << 2;
    const int ty = tid >> 4, tx = tid & 15;
    const int n0 = blockIdx.y * BN;
    int arow;
    if (offp) arow = rowlist[slot0 + ar];
    else      arow = slot0 + ar;
    const float* Aptr = (arow >= 0) ? (Xsrc + (size_t)arow * Kdim) : nullptr;
    float acc[4][4] = {};
    for (int k0 = 0; k0 < Kdim; k0 += BK) {
        float4 av = make_float4(0.f, 0.f, 0.f, 0.f);
        if (Aptr) av = *(const float4*)(Aptr + k0 + ak);
        const float4 bv = *(const float4*)(W + (size_t)(k0 + bkr) * ldw + n0 + bnc);
        __syncthreads();
        As[ak + 0][ar] = av.x; As[ak + 1][ar] = av.y;
        As[ak + 2][ar] = av.z; As[ak + 3][ar] = av.w;
        *(float4*)&Bs[bkr][bnc] = bv;
        __syncthreads();
#pragma unroll
        for (int k = 0; k < BK; ++k) {
            const float4 a4 = *(const float4*)&As[k][ty << 2];
            const float4 b4 = *(const float4*)&Bs[k][tx << 2];
            const float aa[4] = { a4.x, a4.y, a4.z, a4.w };
            const float bb[4] = { b4.x, b4.y, b4.z, b4.w };
#pragma unroll
            for (int i2 = 0; i2 < 4; ++i2)
#pragma unroll
                for (int j2 = 0; j2 < 4; ++j2)
                    acc[i2][j2] += aa[i2] * bb[j2];
        }
    }
    const float4 bb4 = *(const float4*)(bias + n0 + (tx << 2));
    const int lrow0 = blockIdx.x * BM + (ty << 2);
#pragma unroll
    for (int i2 = 0; i2 < 4; ++i2) {
        float4 o;
        o.x = acc[i2][0] + bb4.x; o.y = acc[i2][1] + bb4.y;
        o.z = acc[i2][2] + bb4.z; o.w = acc[i2][3] + bb4.w;
        if (applyGelu) { o.x = gelu_f(o.x); o.y = gelu_f(o.y); o.z = gelu_f(o.z); o.w = gelu_f(o.w); }
        *(float4*)(Hout + (size_t)(lrow0 + i2) * ldw + n0 + (tx << 2)) = o;
    }
}

// ---------------- grouped GEMM2: y = H @ W2_t + b2_t; out[row] += g*y ------
__global__ __launch_bounds__(256) void gemm2_scatter_kernel(
    const float* __restrict__ H, const int* __restrict__ rowlist,
    const int* __restrict__ offp, const float* __restrict__ slotgate,
    const float* __restrict__ W2base, const float* __restrict__ b2base,
    float* __restrict__ outacc, int s0)
{
    const int slot0 = s0 + blockIdx.x * BM;
    if (slot0 >= offp[T]) return;
    int t = 0;
    while (offp[t + 1] <= slot0) ++t;
    const float* W = W2base + (size_t)t * D * D;
    const float* bias = b2base + (size_t)t * D;
    const int tid = threadIdx.x;
    __shared__ float As[BK][BM];
    __shared__ float Bs[BK][BN];
    const int ar = tid >> 2, ak = (tid & 3) << 2;
    const int bkr = tid >> 4, bnc = (tid & 15) << 2;
    const int ty = tid >> 4, tx = tid & 15;
    const int n0 = blockIdx.y * BN;
    const float* Aptr = H + (size_t)(blockIdx.x * BM + ar) * D;
    float acc[4][4] = {};
    for (int k0 = 0; k0 < D; k0 += BK) {
        const float4 av = *(const float4*)(Aptr + k0 + ak);
        const float4 bv = *(const float4*)(W + (size_t)(k0 + bkr) * D + n0 + bnc);
        __syncthreads();
        As[ak + 0][ar] = av.x; As[ak + 1][ar] = av.y;
        As[ak + 2][ar] = av.z; As[ak + 3][ar] = av.w;
        *(float4*)&Bs[bkr][bnc] = bv;
        __syncthreads();
#pragma unroll
        for (int k = 0; k < BK; ++k) {
            const float4 a4 = *(const float4*)&As[k][ty << 2];
            const float4 b4 = *(const float4*)&Bs[k][tx << 2];
            const float aa[4] = { a4.x, a4.y, a4.z, a4.w };
            const float bb[4] = { b4.x, b4.y, b4.z, b4.w };
#pragma unroll
            for (int i2 = 0; i2 < 4; ++i2)
#pragma unroll
                for (int j2 = 0; j2 < 4; ++j2)
                    acc[i2][j2] += aa[i2] * bb[j2];
        }
    }
    const float4 bb4 = *(const float4*)(bias + n0 + (tx << 2));
#pragma unroll
    for (int i2 = 0; i2 < 4; ++i2) {
        const int s = slot0 + (ty << 2) + i2;
        const int row = rowlist[s];
        if (row < 0) continue;
        const float g = slotgate[s];
        float* op = outacc + (size_t)row * D + n0 + (tx << 2);
        atomicAdd(op + 0, g * (acc[i2][0] + bb4.x));
        atomicAdd(op + 1, g * (acc[i2][1] + bb4.y));
        atomicAdd(op + 2, g * (acc[i2][2] + bb4.z));
        atomicAdd(op + 3, g * (acc[i2][3] + bb4.w));
    }
}

// ---------------- residual + LN -------------------------------------------
__global__ __launch_bounds__(256) void ln_kernel(
    float* __restrict__ x, const float* __restrict__ res,
    const float* __restrict__ g, const float* __restrict__ b)
{
    const int row = blockIdx.x, tid = threadIdx.x;
    const int d = tid << 2;
    float4 v = *(float4*)(x + (size_t)row * D + d);
    const float4 r = *(const float4*)(res + (size_t)row * D + d);
    v.x += r.x; v.y += r.y; v.z += r.z; v.w += r.w;
    __shared__ float red[256];
    red[tid] = v.x + v.y + v.z + v.w;
    __syncthreads();
    for (int st = 128; st > 0; st >>= 1) { if (tid < st) red[tid] += red[tid + st]; __syncthreads(); }
    const float mean = red[0] * (1.0f / 1024.0f);
    __syncthreads();
    const float dx0 = v.x - mean, dx1 = v.y - mean, dx2 = v.z - mean, dx3 = v.w - mean;
    red[tid] = dx0 * dx0 + dx1 * dx1 + dx2 * dx2 + dx3 * dx3;
    __syncthreads();
    for (int st = 128; st > 0; st >>= 1) { if (tid < st) red[tid] += red[tid + st]; __syncthreads(); }
    const float rstd = rsqrtf(red[0] * (1.0f / 1024.0f) + 1e-5f);
    const float4 g4 = *(const float4*)(g + d);
    const float4 b4 = *(const float4*)(b + d);
    float4 o;
    o.x = dx0 * rstd * g4.x + b4.x;
    o.y = dx1 * rstd * g4.y + b4.y;
    o.z = dx2 * rstd * g4.z + b4.z;
    o.w = dx3 * rstd * g4.w + b4.w;
    *(float4*)(x + (size_t)row * D + d) = o;
}

// ---------------- final small head: (B,512)x(512,5|6) + bias ---------------
__global__ __launch_bounds__(64) void head_final_kernel(
    const float* __restrict__ Hs, const float* __restrict__ Hd,
    const float* __restrict__ Ws2, const float* __restrict__ bs2,
    const float* __restrict__ Wd2, const float* __restrict__ bd2,
    float* __restrict__ outp)
{
    const int row = blockIdx.x, lane = threadIdx.x;
    float acc[11] = {};
    for (int m = 0; m < 8; ++m) {
        const int k = lane + 64 * m;
        const float hs = Hs[(size_t)row * 512 + k];
#pragma unroll
        for (int j = 0; j < 5; ++j) acc[j] += hs * Ws2[k * 5 + j];
        const float hd = Hd[(size_t)row * 512 + k];
#pragma unroll
        for (int j = 0; j < 6; ++j) acc[5 + j] += hd * Wd2[k * 6 + j];
    }
#pragma unroll
    for (int off = 32; off > 0; off >>= 1)
#pragma unroll
        for (int j = 0; j < 11; ++j) acc[j] += __shfl_down(acc[j], off);
    if (lane == 0) {
        for (int j = 0; j < 5; ++j) outp[(size_t)row * 11 + j] = acc[j] + bs2[j];
        for (int j = 0; j < 6; ++j) outp[(size_t)row * 11 + 5 + j] = acc[5 + j] + bd2[j];
    }
}

// ---------------------------------------------------------------------------
extern "C" void kernel_launch(void* const* d_in, const int* in_sizes, int n_in,
                              void* d_out, int out_size, void* d_ws, size_t ws_size,
                              hipStream_t stream)
{
    const int*   a    = (const int*)d_in[0];
    const int*   bI   = (const int*)d_in[1];
    const float* Win  = (const float*)d_in[2];
    const float* bin_ = (const float*)d_in[3];
    const float* g_in = (const float*)d_in[4];
    const float* b_ln = (const float*)d_in[5];
    const float* Wr   = (const float*)d_in[6];
    const float* W1   = (const float*)d_in[7];
    const float* b1   = (const float*)d_in[8];
    const float* W2   = (const float*)d_in[9];
    const float* b2   = (const float*)d_in[10];
    const float* g_l  = (const float*)d_in[11];
    const float* b_l  = (const float*)d_in[12];
    const float* Ws1  = (const float*)d_in[13];
    const float* bs1  = (const float*)d_in[14];
    const float* Ws2  = (const float*)d_in[15];
    const float* bs2  = (const float*)d_in[16];
    const float* Wd1  = (const float*)d_in[17];
    const float* bd1  = (const float*)d_in[18];
    const float* Wd2  = (const float*)d_in[19];
    const float* bd2  = (const float*)d_in[20];
    const int Bn = in_sizes[0];                 // 16384
    float* outF = (float*)d_out;

    const long maxslots = (long)Bn * KSEL + T * BM;   // padded slot capacity

    // ---- workspace carve (256B aligned) ----
    char* p = (char*)d_ws;
    auto alloc = [&](size_t bytes) -> char* {
        char* r = p;
        p += (bytes + 255) & ~(size_t)255;
        return r;
    };
    float* x        = (float*)alloc((size_t)Bn * D * 4);
    float* outacc   = (float*)alloc((size_t)Bn * D * 4);
    float* gates    = (float*)alloc((size_t)Bn * KSEL * 4);
    float* slotgate = (float*)alloc((size_t)maxslots * 4);
    int*   topi     = (int*)alloc((size_t)Bn * KSEL * 4);
    int*   rowlist  = (int*)alloc((size_t)maxslots * 4);
    int*   counts   = (int*)alloc(T * 4);
    int*   offp     = (int*)alloc((T + 1) * 4);
    int*   cur      = (int*)alloc(T * 4);
    const size_t used = (size_t)(p - (char*)d_ws);
    const size_t avail = (ws_size > used) ? (ws_size - used) : 0;

    long hcap = (long)(avail / ((size_t)D * 4));  // H slots that fit
    hcap &= ~(long)(BM - 1);
    if (hcap > maxslots) hcap = maxslots;
    if (hcap < Bn) hcap = Bn;                     // floor: heads need Bn*512*2 floats here
    float* Hbuf = (float*)p;
    float* Hs = Hbuf;
    float* Hd = Hbuf + (size_t)Bn * 512;
    const int nchunks = (int)((maxslots + hcap - 1) / hcap);
    const int mblocks = (int)(hcap / BM);

    // ---- launches ----
    encode_kernel<<<Bn, 256, 0, stream>>>(a, bI, Win, bin_, g_in, b_ln, x);

    const long initn = (long)Bn * D;
    const int initblocks = (int)((initn + 255) / 256);
    for (int i = 0; i < 3; ++i) {
        init_layer_kernel<<<initblocks, 256, 0, stream>>>(outacc, rowlist, counts,
                                                          initn, (int)maxslots);
        router_kernel<<<Bn, 64, 0, stream>>>(x, Wr, i, gates, topi, counts);
        scan_kernel<<<1, 64, 0, stream>>>(counts, offp, cur);
        scatter_kernel<<<(Bn + 255) / 256, 256, 0, stream>>>(topi, gates, offp, cur,
                                                             rowlist, slotgate, Bn);
        const float* W1i = W1 + (size_t)i * T * D * D;
        const float* b1i = b1 + (size_t)i * T * D;
        const float* W2i = W2 + (size_t)i * T * D * D;
        const float* b2i = b2 + (size_t)i * T * D;
        for (int c = 0; c < nchunks; ++c) {
            const int s0 = (int)((long)c * hcap);
            dim3 grid(mblocks, D / BN);
            gemm_gather_kernel<<<grid, 256, 0, stream>>>(x, rowlist, offp, W1i, b1i,
                                                         Hbuf, s0, D, D, 0, 1);
            gemm2_scatter_kernel<<<grid, 256, 0, stream>>>(Hbuf, rowlist, offp, slotgate,
                                                           W2i, b2i, outacc, s0);
        }
        ln_kernel<<<Bn, 256, 0, stream>>>(x, outacc, g_l + (size_t)i * D, b_l + (size_t)i * D);
    }

    // heads: Hs = gelu(x@Ws1+bs1), Hd = gelu(x@Wd1+bd1)
    dim3 gh(Bn / BM, 512 / BN);
    gemm_gather_kernel<<<gh, 256, 0, stream>>>(x, nullptr, nullptr, Ws1, bs1, Hs, 0, D, 512, Bn, 1);
    gemm_gather_kernel<<<gh, 256, 0, stream>>>(x, nullptr, nullptr, Wd1, bd1, Hd, 0, D, 512, Bn, 1);
    head_final_kernel<<<Bn, 64, 0, stream>>>(Hs, Hd, Ws2, bs2, Wd2, bd2, outF);
}

// Round 2
// 9029.920 us; speedup vs baseline: 1.7717x; 1.7717x over previous
//
#include <hip/hip_runtime.h>
#include <math.h>

// ---------------------------------------------------------------------------
// PureTriXButterfly round 2: split-fp16 3-term MFMA for all big GEMMs.
// Pipeline: encode(+split x) -> per layer { router top-4, scan/scatter to
// 128-padded per-tile slot lists, transpose+split W1/W2 to N-major fp16 hi/lo,
// grouped gather GEMM1 (mfma, gelu, write H hi/lo), grouped GEMM2 (mfma,
// gate*y atomicAdd into outacc), residual LN (+split x) } -> head GEMMs
// (mfma) -> final tiny head.
// Numerics: hi/lo fp16 split keeps effective ~2^-22 precision so router
// top-4 selections match the fp32 reference (flip-safe).
// ---------------------------------------------------------------------------

constexpr int D    = 1024;
constexpr int T    = 16;
constexpr int KSEL = 4;
constexpr int PAD  = 128;   // slot padding per tile = GEMM M-tile

typedef _Float16 f16;
typedef f16 f16x8 __attribute__((ext_vector_type(8)));
typedef f16 f16x4 __attribute__((ext_vector_type(4)));
typedef float f32x4 __attribute__((ext_vector_type(4)));
typedef unsigned int u32;

__device__ __forceinline__ float gelu_f(float v) {
    return 0.5f * v * (1.0f + erff(v * 0.70710678118654752440f));
}

__device__ __forceinline__ void async16(const void* g, void* l) {
    __builtin_amdgcn_global_load_lds(
        (const __attribute__((address_space(1))) u32*)g,
        (__attribute__((address_space(3))) u32*)l, 16, 0, 0);
}

// ---------------- input encode: fourier -> @Win -> LN -> GELU (+split) -----
__global__ __launch_bounds__(256) void encode_kernel(
    const int* __restrict__ A, const int* __restrict__ Bv,
    const float* __restrict__ Win, const float* __restrict__ bin_,
    const float* __restrict__ g_in, const float* __restrict__ b_ln,
    float* __restrict__ x, f16* __restrict__ xhi, f16* __restrict__ xlo)
{
    const int row = blockIdx.x, tid = threadIdx.x;
    const float c = (float)(6.283185307179586476925286766559 / 16.0);
    float feat[32];
    const float xa = (float)A[row] * c;
    const float xb = (float)Bv[row] * c;
#pragma unroll
    for (int k = 0; k < 8; ++k) {
        const float f = (float)(1 << k);
        float aa = xa * f, ab = xb * f;
        feat[k]      = sinf(aa);
        feat[8 + k]  = cosf(aa);
        feat[16 + k] = sinf(ab);
        feat[24 + k] = cosf(ab);
    }
    const int d = tid << 2;
    float4 acc = *(const float4*)(bin_ + d);
#pragma unroll
    for (int f = 0; f < 32; ++f) {
        const float4 w = *(const float4*)(Win + (size_t)f * D + d);
        const float ff = feat[f];
        acc.x += ff * w.x; acc.y += ff * w.y; acc.z += ff * w.z; acc.w += ff * w.w;
    }
    __shared__ float red[256];
    red[tid] = acc.x + acc.y + acc.z + acc.w;
    __syncthreads();
    for (int st = 128; st > 0; st >>= 1) { if (tid < st) red[tid] += red[tid + st]; __syncthreads(); }
    const float mean = red[0] * (1.0f / 1024.0f);
    __syncthreads();
    float dx0 = acc.x - mean, dx1 = acc.y - mean, dx2 = acc.z - mean, dx3 = acc.w - mean;
    red[tid] = dx0 * dx0 + dx1 * dx1 + dx2 * dx2 + dx3 * dx3;
    __syncthreads();
    for (int st = 128; st > 0; st >>= 1) { if (tid < st) red[tid] += red[tid + st]; __syncthreads(); }
    const float rstd = rsqrtf(red[0] * (1.0f / 1024.0f) + 1e-5f);
    const float4 g4 = *(const float4*)(g_in + d);
    const float4 b4 = *(const float4*)(b_ln + d);
    float4 o;
    o.x = gelu_f(dx0 * rstd * g4.x + b4.x);
    o.y = gelu_f(dx1 * rstd * g4.y + b4.y);
    o.z = gelu_f(dx2 * rstd * g4.z + b4.z);
    o.w = gelu_f(dx3 * rstd * g4.w + b4.w);
    *(float4*)(x + (size_t)row * D + d) = o;
    f16x4 hv, lv;
    hv[0] = (f16)o.x; lv[0] = (f16)(o.x - (float)hv[0]);
    hv[1] = (f16)o.y; lv[1] = (f16)(o.y - (float)hv[1]);
    hv[2] = (f16)o.z; lv[2] = (f16)(o.z - (float)hv[2]);
    hv[3] = (f16)o.w; lv[3] = (f16)(o.w - (float)hv[3]);
    *(f16x4*)(xhi + (size_t)row * D + d) = hv;
    *(f16x4*)(xlo + (size_t)row * D + d) = lv;
}

// ---------------- per-layer init ------------------------------------------
__global__ __launch_bounds__(256) void init_layer_kernel(
    float* __restrict__ outacc, int* __restrict__ rowlist, int* __restrict__ counts,
    long n, int maxslots)
{
    const long i = (long)blockIdx.x * blockDim.x + threadIdx.x;
    if (i < n) outacc[i] = 0.0f;
    if (i < maxslots) rowlist[i] = -1;
    if (i < T) counts[i] = 0;
}

// ---------------- router: logits, softmax, top-4 ---------------------------
__global__ __launch_bounds__(64) void router_kernel(
    const float* __restrict__ x, const float* __restrict__ Wr, int layer,
    float* __restrict__ gates, int* __restrict__ topi, int* __restrict__ counts)
{
    const int row = blockIdx.x, lane = threadIdx.x;
    __shared__ float xs[D];
    __shared__ float ls[T];
    for (int j = lane; j < D / 4; j += 64)
        *(float4*)&xs[j * 4] = *(const float4*)(x + (size_t)row * D + j * 4);
    __syncthreads();
    const int t = lane & 15, seg = lane >> 4;
    const float* wr = Wr + (size_t)layer * D * T;
    float acc = 0.0f;
    const int d0 = seg * 256;
    for (int j = 0; j < 256; ++j) {
        const int d = d0 + j;
        acc += xs[d] * wr[d * T + t];
    }
    acc += __shfl_down(acc, 32);
    acc += __shfl_down(acc, 16);
    if (lane < 16) ls[lane] = acc;
    __syncthreads();
    if (lane == 0) {
        float m = ls[0];
        for (int i = 1; i < 16; ++i) m = fmaxf(m, ls[i]);
        float p[16], ssum = 0.0f;
        for (int i = 0; i < 16; ++i) { p[i] = expf(ls[i] - m); ssum += p[i]; }
        const float inv = 1.0f / ssum;
        bool sel[16];
        for (int i = 0; i < 16; ++i) sel[i] = false;
        for (int j = 0; j < KSEL; ++j) {
            int best = 0; float bvv = -1e30f;
            for (int i = 0; i < 16; ++i)
                if (!sel[i] && ls[i] > bvv) { bvv = ls[i]; best = i; }
            sel[best] = true;
            topi[row * KSEL + j]  = best;
            gates[row * KSEL + j] = p[best] * inv;
            atomicAdd(&counts[best], 1);
        }
    }
}

// ---------------- scan: padded per-tile offsets ----------------------------
__global__ void scan_kernel(const int* __restrict__ counts, int* __restrict__ offp,
                            int* __restrict__ cur)
{
    if (threadIdx.x == 0) {
        int off = 0;
        for (int t = 0; t < T; ++t) {
            offp[t] = off;
            cur[t] = 0;
            off += ((counts[t] + PAD - 1) / PAD) * PAD;
        }
        offp[T] = off;
    }
}

// ---------------- scatter rows into tile slot lists ------------------------
__global__ __launch_bounds__(256) void scatter_kernel(
    const int* __restrict__ topi, const float* __restrict__ gates,
    const int* __restrict__ offp, int* __restrict__ cur,
    int* __restrict__ rowlist, float* __restrict__ slotgate, int Bn)
{
    const int row = blockIdx.x * blockDim.x + threadIdx.x;
    if (row >= Bn) return;
    for (int j = 0; j < KSEL; ++j) {
        const int t = topi[row * KSEL + j];
        const int pos = atomicAdd(&cur[t], 1);
        const int s = offp[t] + pos;
        rowlist[s] = row;
        slotgate[s] = gates[row * KSEL + j];
    }
}

// ---------------- transpose + hi/lo split: W(K,N) fp32 -> Wt(N,K) f16 ------
__global__ __launch_bounds__(256) void tspl_kernel(
    const float* __restrict__ W, f16* __restrict__ ohi, f16* __restrict__ olo,
    int K, int N)
{
    const size_t zoff = (size_t)blockIdx.z * K * N;
    const float* Wz = W + zoff;
    const int r0 = blockIdx.x * 32, c0 = blockIdx.y * 32;
    __shared__ float tile[32][33];
    const int tr = threadIdx.x >> 3, tc = (threadIdx.x & 7) * 4;
    const float4 v = *(const float4*)(Wz + (size_t)(r0 + tr) * N + c0 + tc);
    tile[tr][tc + 0] = v.x; tile[tr][tc + 1] = v.y;
    tile[tr][tc + 2] = v.z; tile[tr][tc + 3] = v.w;
    __syncthreads();
    f16x4 h4, l4;
#pragma unroll
    for (int q = 0; q < 4; ++q) {
        const float f = tile[tc + q][tr];
        const f16 h = (f16)f;
        h4[q] = h; l4[q] = (f16)(f - (float)h);
    }
    const size_t oidx = zoff + (size_t)(c0 + tr) * K + r0 + tc;
    *(f16x4*)(ohi + oidx) = h4;
    *(f16x4*)(olo + oidx) = l4;
}

// ---------------- split-fp16 MFMA grouped GEMM -----------------------------
// C(128x128) = A(128x1024) @ B(1024x128), 3-term hi/lo split, fp32 accum.
// mode 0: FFN GEMM1  - A gathered from x planes via rowlist; gelu; H hi/lo out
// mode 1: FFN GEMM2  - A = H planes (chunk-local); gate * y atomicAdd outF
// mode 2: head GEMM  - A = x planes (row = slot); gelu; fp32 out (ld Ncols)
__global__ __launch_bounds__(256) void mfma_gemm_kernel(
    const f16* __restrict__ Ahi, const f16* __restrict__ Alo,
    const int* __restrict__ rowlist, const int* __restrict__ offp,
    const f16* __restrict__ Whi, const f16* __restrict__ Wlo,
    const float* __restrict__ biasbase, const float* __restrict__ slotgate,
    f16* __restrict__ Hhi, f16* __restrict__ Hlo,
    float* __restrict__ outF,
    int mode, int s0, int Ncols, int plainM)
{
    const int slot0 = s0 + blockIdx.x * 128;
    int t = 0;
    if (mode != 2) {
        if (slot0 >= offp[T]) return;
        while (offp[t + 1] <= slot0) ++t;
    } else {
        if (slot0 >= plainM) return;
    }
    const int tid = threadIdx.x;
    const int wave = tid >> 6, lane = tid & 63;
    const int n0 = blockIdx.y * 128;

    // LDS: [buf 0=Ahi 1=Alo 2=Bhi 3=Blo][k-quad][row-or-col][8 halves] = 32 KB
    __shared__ f16 lds[4][4][128][8];

    // 32 wave-issues per K-step; wave w takes iss = w + 4*s (wave-uniform
    // buffer/base per issue; per-lane global addresses may scatter).
    const f16* gp[8];
    f16* lp[8];
#pragma unroll
    for (int s = 0; s < 8; ++s) {
        const int iss = wave + 4 * s;
        const int b = iss >> 3, sub = iss & 7;
        const int c = sub * 64 + lane;
        const int q = c >> 7, idx = c & 127;
        lp[s] = &lds[0][0][0][0] + ((size_t)b * 4096 + (size_t)c * 8);
        if (b < 2) {
            const f16* plane = b ? Alo : Ahi;
            int row;
            if (mode == 0) { const int r = rowlist[slot0 + idx]; row = r < 0 ? 0 : r; }
            else if (mode == 1) row = slot0 - s0 + idx;
            else row = slot0 + idx;
            gp[s] = plane + (size_t)row * 1024 + q * 8;
        } else {
            const f16* plane = (b == 3) ? Wlo : Whi;
            gp[s] = plane + ((size_t)t * Ncols + n0 + idx) * 1024 + q * 8;
        }
    }

    f32x4 acc[4][4];
#pragma unroll
    for (int i = 0; i < 4; ++i)
#pragma unroll
        for (int j = 0; j < 4; ++j) acc[i][j] = (f32x4){0.f, 0.f, 0.f, 0.f};

    const int wr = wave >> 1, wc = wave & 1;
    const int qd = lane >> 4, m16 = lane & 15;

    for (int k0 = 0; k0 < 1024; k0 += 32) {
        __syncthreads();   // prior frag reads done before LDS overwrite
#pragma unroll
        for (int s = 0; s < 8; ++s) { async16(gp[s], lp[s]); gp[s] += 32; }
        __syncthreads();   // staging loads drained (vmcnt) + visible
        f16x8 ah[4], al[4], bh[4], bl[4];
#pragma unroll
        for (int i = 0; i < 4; ++i) {
            ah[i] = *(const f16x8*)&lds[0][qd][wr * 64 + i * 16 + m16][0];
            al[i] = *(const f16x8*)&lds[1][qd][wr * 64 + i * 16 + m16][0];
            bh[i] = *(const f16x8*)&lds[2][qd][wc * 64 + i * 16 + m16][0];
            bl[i] = *(const f16x8*)&lds[3][qd][wc * 64 + i * 16 + m16][0];
        }
#pragma unroll
        for (int i = 0; i < 4; ++i)
#pragma unroll
            for (int j = 0; j < 4; ++j) {
                acc[i][j] = __builtin_amdgcn_mfma_f32_16x16x32_f16(ah[i], bh[j], acc[i][j], 0, 0, 0);
                acc[i][j] = __builtin_amdgcn_mfma_f32_16x16x32_f16(al[i], bh[j], acc[i][j], 0, 0, 0);
                acc[i][j] = __builtin_amdgcn_mfma_f32_16x16x32_f16(ah[i], bl[j], acc[i][j], 0, 0, 0);
            }
    }

    float bj[4];
#pragma unroll
    for (int j = 0; j < 4; ++j)
        bj[j] = biasbase[(size_t)t * Ncols + n0 + wc * 64 + j * 16 + m16];

    if (mode == 0) {
#pragma unroll
        for (int i = 0; i < 4; ++i)
#pragma unroll
            for (int r = 0; r < 4; ++r) {
                const int ls_ = slot0 - s0 + wr * 64 + i * 16 + qd * 4 + r;
                f16* ph = Hhi + (size_t)ls_ * 1024 + n0 + wc * 64 + m16;
                f16* pl = Hlo + (size_t)ls_ * 1024 + n0 + wc * 64 + m16;
#pragma unroll
                for (int j = 0; j < 4; ++j) {
                    const float v = gelu_f(acc[i][j][r] + bj[j]);
                    const f16 h = (f16)v;
                    ph[j * 16] = h;
                    pl[j * 16] = (f16)(v - (float)h);
                }
            }
    } else if (mode == 1) {
#pragma unroll
        for (int i = 0; i < 4; ++i)
#pragma unroll
            for (int r = 0; r < 4; ++r) {
                const int s_ = slot0 + wr * 64 + i * 16 + qd * 4 + r;
                const int grow = rowlist[s_];
                if (grow < 0) continue;
                const float g = slotgate[s_];
                float* op = outF + (size_t)grow * 1024 + n0 + wc * 64 + m16;
#pragma unroll
                for (int j = 0; j < 4; ++j)
                    atomicAdd(op + j * 16, g * (acc[i][j][r] + bj[j]));
            }
    } else {
#pragma unroll
        for (int i = 0; i < 4; ++i)
#pragma unroll
            for (int r = 0; r < 4; ++r) {
                const int row = slot0 + wr * 64 + i * 16 + qd * 4 + r;
                float* op = outF + (size_t)row * Ncols + n0 + wc * 64 + m16;
#pragma unroll
                for (int j = 0; j < 4; ++j)
                    op[j * 16] = gelu_f(acc[i][j][r] + bj[j]);
            }
    }
}

// ---------------- residual + LN (+split x) ---------------------------------
__global__ __launch_bounds__(256) void ln_kernel(
    float* __restrict__ x, const float* __restrict__ res,
    const float* __restrict__ g, const float* __restrict__ b,
    f16* __restrict__ xhi, f16* __restrict__ xlo)
{
    const int row = blockIdx.x, tid = threadIdx.x;
    const int d = tid << 2;
    float4 v = *(float4*)(x + (size_t)row * D + d);
    const float4 r = *(const float4*)(res + (size_t)row * D + d);
    v.x += r.x; v.y += r.y; v.z += r.z; v.w += r.w;
    __shared__ float red[256];
    red[tid] = v.x + v.y + v.z + v.w;
    __syncthreads();
    for (int st = 128; st > 0; st >>= 1) { if (tid < st) red[tid] += red[tid + st]; __syncthreads(); }
    const float mean = red[0] * (1.0f / 1024.0f);
    __syncthreads();
    const float dx0 = v.x - mean, dx1 = v.y - mean, dx2 = v.z - mean, dx3 = v.w - mean;
    red[tid] = dx0 * dx0 + dx1 * dx1 + dx2 * dx2 + dx3 * dx3;
    __syncthreads();
    for (int st = 128; st > 0; st >>= 1) { if (tid < st) red[tid] += red[tid + st]; __syncthreads(); }
    const float rstd = rsqrtf(red[0] * (1.0f / 1024.0f) + 1e-5f);
    const float4 g4 = *(const float4*)(g + d);
    const float4 b4 = *(const float4*)(b + d);
    float4 o;
    o.x = dx0 * rstd * g4.x + b4.x;
    o.y = dx1 * rstd * g4.y + b4.y;
    o.z = dx2 * rstd * g4.z + b4.z;
    o.w = dx3 * rstd * g4.w + b4.w;
    *(float4*)(x + (size_t)row * D + d) = o;
    f16x4 hv, lv;
    hv[0] = (f16)o.x; lv[0] = (f16)(o.x - (float)hv[0]);
    hv[1] = (f16)o.y; lv[1] = (f16)(o.y - (float)hv[1]);
    hv[2] = (f16)o.z; lv[2] = (f16)(o.z - (float)hv[2]);
    hv[3] = (f16)o.w; lv[3] = (f16)(o.w - (float)hv[3]);
    *(f16x4*)(xhi + (size_t)row * D + d) = hv;
    *(f16x4*)(xlo + (size_t)row * D + d) = lv;
}

// ---------------- final small head ----------------------------------------
__global__ __launch_bounds__(64) void head_final_kernel(
    const float* __restrict__ Hs, const float* __restrict__ Hd,
    const float* __restrict__ Ws2, const float* __restrict__ bs2,
    const float* __restrict__ Wd2, const float* __restrict__ bd2,
    float* __restrict__ outp)
{
    const int row = blockIdx.x, lane = threadIdx.x;
    float acc[11] = {};
    for (int m = 0; m < 8; ++m) {
        const int k = lane + 64 * m;
        const float hs = Hs[(size_t)row * 512 + k];
#pragma unroll
        for (int j = 0; j < 5; ++j) acc[j] += hs * Ws2[k * 5 + j];
        const float hd = Hd[(size_t)row * 512 + k];
#pragma unroll
        for (int j = 0; j < 6; ++j) acc[5 + j] += hd * Wd2[k * 6 + j];
    }
#pragma unroll
    for (int off = 32; off > 0; off >>= 1)
#pragma unroll
        for (int j = 0; j < 11; ++j) acc[j] += __shfl_down(acc[j], off);
    if (lane == 0) {
        for (int j = 0; j < 5; ++j) outp[(size_t)row * 11 + j] = acc[j] + bs2[j];
        for (int j = 0; j < 6; ++j) outp[(size_t)row * 11 + 5 + j] = acc[5 + j] + bd2[j];
    }
}

// ---------------------------------------------------------------------------
extern "C" void kernel_launch(void* const* d_in, const int* in_sizes, int n_in,
                              void* d_out, int out_size, void* d_ws, size_t ws_size,
                              hipStream_t stream)
{
    const int*   a    = (const int*)d_in[0];
    const int*   bI   = (const int*)d_in[1];
    const float* Win  = (const float*)d_in[2];
    const float* bin_ = (const float*)d_in[3];
    const float* g_in = (const float*)d_in[4];
    const float* b_ln = (const float*)d_in[5];
    const float* Wr   = (const float*)d_in[6];
    const float* W1   = (const float*)d_in[7];
    const float* b1   = (const float*)d_in[8];
    const float* W2   = (const float*)d_in[9];
    const float* b2   = (const float*)d_in[10];
    const float* g_l  = (const float*)d_in[11];
    const float* b_l  = (const float*)d_in[12];
    const float* Ws1  = (const float*)d_in[13];
    const float* bs1  = (const float*)d_in[14];
    const float* Ws2  = (const float*)d_in[15];
    const float* bs2  = (const float*)d_in[16];
    const float* Wd1  = (const float*)d_in[17];
    const float* bd1  = (const float*)d_in[18];
    const float* Wd2  = (const float*)d_in[19];
    const float* bd2  = (const float*)d_in[20];
    const int Bn = in_sizes[0];                 // 16384
    float* outF = (float*)d_out;

    const long maxslots = (long)Bn * KSEL + (long)T * PAD;  // 67584

    // ---- workspace carve (256 B aligned) ----
    char* p = (char*)d_ws;
    auto alloc = [&](size_t bytes) -> char* {
        char* r = p;
        p += (bytes + 255) & ~(size_t)255;
        return r;
    };
    float* x      = (float*)alloc((size_t)Bn * D * 4);
    f16*   xhi    = (f16*)alloc((size_t)Bn * D * 2);
    f16*   xlo    = (f16*)alloc((size_t)Bn * D * 2);
    float* outacc = (float*)alloc((size_t)Bn * D * 4);
    f16* WtAh = (f16*)alloc((size_t)T * D * D * 2);
    f16* WtAl = (f16*)alloc((size_t)T * D * D * 2);
    f16* WtBh = (f16*)alloc((size_t)T * D * D * 2);
    f16* WtBl = (f16*)alloc((size_t)T * D * D * 2);
    f16* Wtsh = (f16*)alloc((size_t)D * 512 * 2);
    f16* Wtsl = (f16*)alloc((size_t)D * 512 * 2);
    f16* Wtdh = (f16*)alloc((size_t)D * 512 * 2);
    f16* Wtdl = (f16*)alloc((size_t)D * 512 * 2);
    float* gates    = (float*)alloc((size_t)Bn * KSEL * 4);
    float* slotgate = (float*)alloc((size_t)maxslots * 4);
    int*   topi     = (int*)alloc((size_t)Bn * KSEL * 4);
    int*   rowlist  = (int*)alloc((size_t)maxslots * 4);
    int*   counts   = (int*)alloc(T * 4);
    int*   offp     = (int*)alloc((T + 1) * 4);
    int*   cur      = (int*)alloc(T * 4);
    const size_t used = (size_t)(p - (char*)d_ws);
    const size_t avail = (ws_size > used) ? (ws_size - used) : 0;

    // H chunk: Hhi+Hlo = 4096 B per slot. Heads later overlay fp32 Hs/Hd here.
    long hcap = (long)(avail / 4096);
    hcap &= ~(long)(PAD - 1);
    if (hcap > maxslots) hcap = maxslots;
    if (hcap < Bn) hcap = Bn;    // floor so head buffers (Bn*512*2 fp32) fit
    f16* Hhi = (f16*)p;
    f16* Hlo = Hhi + (size_t)hcap * D;
    float* Hs = (float*)p;
    float* Hd = Hs + (size_t)Bn * 512;
    const int nchunks = (int)((maxslots + hcap - 1) / hcap);
    const int mblocks = (int)(hcap / PAD);

    // ---- launches ----
    encode_kernel<<<Bn, 256, 0, stream>>>(a, bI, Win, bin_, g_in, b_ln, x, xhi, xlo);
    tspl_kernel<<<dim3(32, 16, 1), 256, 0, stream>>>(Ws1, Wtsh, Wtsl, D, 512);
    tspl_kernel<<<dim3(32, 16, 1), 256, 0, stream>>>(Wd1, Wtdh, Wtdl, D, 512);

    const long initn = (long)Bn * D;
    const int initblocks = (int)((initn + 255) / 256);
    for (int i = 0; i < 3; ++i) {
        init_layer_kernel<<<initblocks, 256, 0, stream>>>(outacc, rowlist, counts,
                                                          initn, (int)maxslots);
        router_kernel<<<Bn, 64, 0, stream>>>(x, Wr, i, gates, topi, counts);
        scan_kernel<<<1, 64, 0, stream>>>(counts, offp, cur);
        scatter_kernel<<<(Bn + 255) / 256, 256, 0, stream>>>(topi, gates, offp, cur,
                                                             rowlist, slotgate, Bn);
        tspl_kernel<<<dim3(32, 32, 16), 256, 0, stream>>>(W1 + (size_t)i * T * D * D,
                                                          WtAh, WtAl, D, D);
        tspl_kernel<<<dim3(32, 32, 16), 256, 0, stream>>>(W2 + (size_t)i * T * D * D,
                                                          WtBh, WtBl, D, D);
        const float* b1i = b1 + (size_t)i * T * D;
        const float* b2i = b2 + (size_t)i * T * D;
        for (int c = 0; c < nchunks; ++c) {
            const int s0 = (int)((long)c * hcap);
            dim3 grid(mblocks, D / 128);
            mfma_gemm_kernel<<<grid, 256, 0, stream>>>(
                xhi, xlo, rowlist, offp, WtAh, WtAl, b1i, nullptr,
                Hhi, Hlo, nullptr, 0, s0, D, 0);
            mfma_gemm_kernel<<<grid, 256, 0, stream>>>(
                Hhi, Hlo, rowlist, offp, WtBh, WtBl, b2i, slotgate,
                nullptr, nullptr, outacc, 1, s0, D, 0);
        }
        ln_kernel<<<Bn, 256, 0, stream>>>(x, outacc, g_l + (size_t)i * D,
                                          b_l + (size_t)i * D, xhi, xlo);
    }

    // heads: Hs = gelu(x@Ws1+bs1), Hd = gelu(x@Wd1+bd1) via MFMA, then tiny head
    dim3 gh(Bn / 128, 512 / 128);
    mfma_gemm_kernel<<<gh, 256, 0, stream>>>(
        xhi, xlo, nullptr, nullptr, Wtsh, Wtsl, bs1, nullptr,
        nullptr, nullptr, Hs, 2, 0, 512, Bn);
    mfma_gemm_kernel<<<gh, 256, 0, stream>>>(
        xhi, xlo, nullptr, nullptr, Wtdh, Wtdl, bd1, nullptr,
        nullptr, nullptr, Hd, 2, 0, 512, Bn);
    head_final_kernel<<<Bn, 64, 0, stream>>>(Hs, Hd, Ws2, bs2, Wd2, bd2, outF);
}